// Round 1
// baseline (1580.964 us; speedup 1.0000x reference)
//
#include <hip/hip_runtime.h>

#define CH      128
#define RBFD    200
#define NNODES  50000
#define NEDGES  600000
#define LOG2F_  0.6931471805599453f

__device__ __forceinline__ float ssp(float x) {
    // shifted softplus: (x<14 ? log1p(exp(x)) : x) - log(2)
    float sp = (x < 14.0f) ? log1pf(__expf(x)) : x;
    return sp - LOG2F_;
}

// ---------------- f = x @ w3  (N x 128) ----------------
__global__ __launch_bounds__(256) void node_fw3(const float* __restrict__ x,
                                                const float* __restrict__ w3,
                                                float* __restrict__ f,
                                                int n_nodes) {
    __shared__ float xs[32 * 128];
    const int t = threadIdx.x;
    const int n0 = blockIdx.x * 32;
    const int rows = min(32, n_nodes - n0);

    const float4* g = (const float4*)(x + (size_t)n0 * CH);
    float4* s = (float4*)xs;
    const int total = rows * 32;               // float4 per row = 32
    for (int i = t; i < total; i += 256) s[i] = g[i];
    __syncthreads();

    const int c = t & 127, eh = t >> 7;
    float acc[16];
#pragma unroll
    for (int i = 0; i < 16; i++) acc[i] = 0.f;

    for (int k = 0; k < 128; k += 4) {
        const float wa = w3[(k + 0) * CH + c];
        const float wb = w3[(k + 1) * CH + c];
        const float wc = w3[(k + 2) * CH + c];
        const float wd = w3[(k + 3) * CH + c];
#pragma unroll
        for (int i = 0; i < 16; i++) {
            const float4 v = *(const float4*)&xs[(eh * 16 + i) * CH + k];
            acc[i] = fmaf(v.x, wa, acc[i]);
            acc[i] = fmaf(v.y, wb, acc[i]);
            acc[i] = fmaf(v.z, wc, acc[i]);
            acc[i] = fmaf(v.w, wd, acc[i]);
        }
    }
#pragma unroll
    for (int i = 0; i < 16; i++) {
        const int r = eh * 16 + i;
        if (r < rows) f[((size_t)(n0 + r)) * CH + c] = acc[i];
    }
}

// -------- fused edge pipeline: h=ssp(rbf@w1+b1); w=ssp(h@w2+b2);
//          scatter-add w * f[src] into conv[src] --------
__global__ __launch_bounds__(256) void edge_kernel(const float* __restrict__ rbf,
                                                   const float* __restrict__ w1,
                                                   const float* __restrict__ b1,
                                                   const float* __restrict__ w2,
                                                   const float* __restrict__ b2,
                                                   const int* __restrict__ src,
                                                   const float* __restrict__ f,
                                                   float* __restrict__ conv) {
    __shared__ float rbf_s[32 * RBFD];   // 25.6 KB
    __shared__ float h_s[32 * CH];       // 16 KB
    const int t = threadIdx.x;
    const size_t e0 = (size_t)blockIdx.x * 32;

    // stage rbf tile: 32*200 = 6400 floats = 1600 float4, contiguous in global
    {
        const float4* g = (const float4*)(rbf + e0 * RBFD);
        float4* s = (float4*)rbf_s;
        for (int i = t; i < 1600; i += 256) s[i] = g[i];
    }
    __syncthreads();

    const int c = t & 127, eh = t >> 7;
    float acc[16];
#pragma unroll
    for (int i = 0; i < 16; i++) acc[i] = 0.f;

    // ---- phase 2: h = ssp(rbf @ w1 + b1) ----
    for (int k = 0; k < RBFD; k += 4) {
        const float wa = w1[(k + 0) * CH + c];
        const float wb = w1[(k + 1) * CH + c];
        const float wc = w1[(k + 2) * CH + c];
        const float wd = w1[(k + 3) * CH + c];
#pragma unroll
        for (int i = 0; i < 16; i++) {
            const float4 v = *(const float4*)&rbf_s[(eh * 16 + i) * RBFD + k];
            acc[i] = fmaf(v.x, wa, acc[i]);
            acc[i] = fmaf(v.y, wb, acc[i]);
            acc[i] = fmaf(v.z, wc, acc[i]);
            acc[i] = fmaf(v.w, wd, acc[i]);
        }
    }
    {
        const float bias1 = b1[c];
#pragma unroll
        for (int i = 0; i < 16; i++)
            h_s[(eh * 16 + i) * CH + c] = ssp(acc[i] + bias1);
    }
    __syncthreads();

    // ---- phase 3: w = ssp(h @ w2 + b2) ----
#pragma unroll
    for (int i = 0; i < 16; i++) acc[i] = 0.f;
    for (int k = 0; k < CH; k += 4) {
        const float wa = w2[(k + 0) * CH + c];
        const float wb = w2[(k + 1) * CH + c];
        const float wc = w2[(k + 2) * CH + c];
        const float wd = w2[(k + 3) * CH + c];
#pragma unroll
        for (int i = 0; i < 16; i++) {
            const float4 v = *(const float4*)&h_s[(eh * 16 + i) * CH + k];
            acc[i] = fmaf(v.x, wa, acc[i]);
            acc[i] = fmaf(v.y, wb, acc[i]);
            acc[i] = fmaf(v.z, wc, acc[i]);
            acc[i] = fmaf(v.w, wd, acc[i]);
        }
    }

    // ---- phase 4: gather f[src], multiply, scatter-add into conv ----
    {
        const float bias2 = b2[c];
#pragma unroll
        for (int i = 0; i < 16; i++) {
            const int e = eh * 16 + i;
            const int sidx = src[e0 + e];          // wave-uniform -> scalar load
            const float wv = ssp(acc[i] + bias2);
            const size_t off = (size_t)sidx * CH + c;
            atomicAdd(&conv[off], wv * f[off]);
        }
    }
}

// -------- out = x + (ssp(conv@w4+b4) @ w5 + b5) --------
__global__ __launch_bounds__(256) void node_out(const float* __restrict__ conv,
                                                const float* __restrict__ w4,
                                                const float* __restrict__ b4,
                                                const float* __restrict__ w5,
                                                const float* __restrict__ b5,
                                                const float* __restrict__ x,
                                                float* __restrict__ out,
                                                int n_nodes) {
    __shared__ float cs[32 * 128];
    __shared__ float ys[32 * 128];
    const int t = threadIdx.x;
    const int n0 = blockIdx.x * 32;
    const int rows = min(32, n_nodes - n0);

    {
        const float4* g = (const float4*)(conv + (size_t)n0 * CH);
        float4* s = (float4*)cs;
        const int total = rows * 32;
        for (int i = t; i < total; i += 256) s[i] = g[i];
    }
    __syncthreads();

    const int c = t & 127, eh = t >> 7;
    float acc[16];
#pragma unroll
    for (int i = 0; i < 16; i++) acc[i] = 0.f;

    // y = ssp(conv @ w4 + b4)
    for (int k = 0; k < 128; k += 4) {
        const float wa = w4[(k + 0) * CH + c];
        const float wb = w4[(k + 1) * CH + c];
        const float wc = w4[(k + 2) * CH + c];
        const float wd = w4[(k + 3) * CH + c];
#pragma unroll
        for (int i = 0; i < 16; i++) {
            const float4 v = *(const float4*)&cs[(eh * 16 + i) * CH + k];
            acc[i] = fmaf(v.x, wa, acc[i]);
            acc[i] = fmaf(v.y, wb, acc[i]);
            acc[i] = fmaf(v.z, wc, acc[i]);
            acc[i] = fmaf(v.w, wd, acc[i]);
        }
    }
    {
        const float bias4 = b4[c];
#pragma unroll
        for (int i = 0; i < 16; i++)
            ys[(eh * 16 + i) * CH + c] = ssp(acc[i] + bias4);
    }
    __syncthreads();

    // v = y @ w5 + b5 ; out = x + v
#pragma unroll
    for (int i = 0; i < 16; i++) acc[i] = 0.f;
    for (int k = 0; k < 128; k += 4) {
        const float wa = w5[(k + 0) * CH + c];
        const float wb = w5[(k + 1) * CH + c];
        const float wc = w5[(k + 2) * CH + c];
        const float wd = w5[(k + 3) * CH + c];
#pragma unroll
        for (int i = 0; i < 16; i++) {
            const float4 v = *(const float4*)&ys[(eh * 16 + i) * CH + k];
            acc[i] = fmaf(v.x, wa, acc[i]);
            acc[i] = fmaf(v.y, wb, acc[i]);
            acc[i] = fmaf(v.z, wc, acc[i]);
            acc[i] = fmaf(v.w, wd, acc[i]);
        }
    }
    {
        const float bias5 = b5[c];
#pragma unroll
        for (int i = 0; i < 16; i++) {
            const int r = eh * 16 + i;
            if (r < rows) {
                const size_t off = ((size_t)(n0 + r)) * CH + c;
                out[off] = x[off] + acc[i] + bias5;
            }
        }
    }
}

extern "C" void kernel_launch(void* const* d_in, const int* in_sizes, int n_in,
                              void* d_out, int out_size, void* d_ws, size_t ws_size,
                              hipStream_t stream) {
    const float* rbf = (const float*)d_in[0];
    const float* x   = (const float*)d_in[1];
    const int*   src = (const int*)d_in[2];
    const float* w1  = (const float*)d_in[3];
    const float* b1  = (const float*)d_in[4];
    const float* w2  = (const float*)d_in[5];
    const float* b2  = (const float*)d_in[6];
    const float* w3  = (const float*)d_in[7];
    const float* w4  = (const float*)d_in[8];
    const float* b4  = (const float*)d_in[9];
    const float* w5  = (const float*)d_in[10];
    const float* b5  = (const float*)d_in[11];

    float* out  = (float*)d_out;
    float* conv = (float*)d_ws;     // [N,128] accumulator, 25.6 MB
    float* f    = out;              // stage f = x@w3 in d_out (dead until node_out)

    hipMemsetAsync(conv, 0, (size_t)NNODES * CH * sizeof(float), stream);

    node_fw3<<<(NNODES + 31) / 32, 256, 0, stream>>>(x, w3, f, NNODES);
    edge_kernel<<<NEDGES / 32, 256, 0, stream>>>(rbf, w1, b1, w2, b2, src, f, conv);
    node_out<<<(NNODES + 31) / 32, 256, 0, stream>>>(conv, w4, b4, w5, b5, x, out, NNODES);
}

// Round 2
// 490.340 us; speedup vs baseline: 3.2242x; 3.2242x over previous
//
#include <hip/hip_runtime.h>

#define CH      128
#define RBFD    200
#define NNODES  50000
#define NEDGES  600000
#define LOG2F_  0.6931471805599453f

// K padded to 224 for GEMM1 (7 k-tiles of 32); LDS row strides padded for banks
#define K1P     224
#define RSTR    232     // rbf_s row stride in bf16 elems (464 B -> 20 banks mod 32)
#define HSTR    136     // h_s row stride  in bf16 elems (272 B -> 4 banks mod 32)

typedef __attribute__((ext_vector_type(8))) __bf16 bf16x8;
typedef __attribute__((ext_vector_type(4))) float  f32x4;

__device__ __forceinline__ float ssp(float x) {
    // shifted softplus, fast: log(1+e^x) via hw exp/log (abs err ~1e-7, fine vs 0.24 tol)
    float sp = (x < 14.0f) ? __logf(1.0f + __expf(x)) : x;
    return sp - LOG2F_;
}

__device__ __forceinline__ unsigned short f2bf(float f) {
    union { float f; unsigned int u; } v; v.f = f;
    unsigned int r = v.u + 0x7FFFu + ((v.u >> 16) & 1u);   // RNE (finite inputs)
    return (unsigned short)(r >> 16);
}

// ---- prep: bf16-transposed weights  w1T[128][224] (zero-padded), w2T[128][128] ----
__global__ __launch_bounds__(256) void prep_weights(const float* __restrict__ w1,
                                                    const float* __restrict__ w2,
                                                    unsigned short* __restrict__ w1T,
                                                    unsigned short* __restrict__ w2T) {
    int i = blockIdx.x * 256 + threadIdx.x;
    if (i < 128 * K1P) {
        int n = i / K1P, k = i % K1P;
        w1T[i] = (k < RBFD) ? f2bf(w1[k * CH + n]) : (unsigned short)0;
    } else {
        int j = i - 128 * K1P;
        if (j < 128 * 128) {
            int n = j / 128, k = j % 128;
            w2T[j] = f2bf(w2[k * CH + n]);
        }
    }
}

// ---- edge pipeline: w = ssp(ssp(rbf@w1+b1)@w2+b2); atomicAdd into convw[src] ----
__global__ __launch_bounds__(256, 3) void edge_kernel(const float* __restrict__ rbf,
                                                      const float* __restrict__ b1,
                                                      const float* __restrict__ b2,
                                                      const int* __restrict__ src,
                                                      const unsigned short* __restrict__ w1T,
                                                      const unsigned short* __restrict__ w2T,
                                                      float* __restrict__ convw) {
    __shared__ unsigned short rbf_s[64 * RSTR];   // 29696 B
    __shared__ unsigned short h_s[64 * HSTR];     // 17408 B
    const int t = threadIdx.x;
    const int lane = t & 63;
    const int wv = t >> 6;                        // wave id 0..3, owns cols [wv*32, wv*32+32)
    const size_t e0 = (size_t)blockIdx.x * 64;

    const int l15 = lane & 15;
    const int lg  = lane >> 4;                    // 0..3 k-group
    const int col0 = wv * 32 + l15;

    // ---- preload B1 fragments (w1T rows = output cols), 2 n-tiles x 7 k-tiles ----
    bf16x8 B1[2][7];
#pragma unroll
    for (int nt = 0; nt < 2; nt++) {
        const int row = wv * 32 + nt * 16 + l15;
#pragma unroll
        for (int kt = 0; kt < 7; kt++)
            B1[nt][kt] = *(const bf16x8*)(w1T + (size_t)row * K1P + kt * 32 + lg * 8);
    }

    // ---- stage rbf tile [64][200] fp32 -> bf16 LDS, zero-pad k=200..231 ----
    {
        const float4* g = (const float4*)(rbf + e0 * RBFD);
        for (int i = t; i < 3200; i += 256) {
            float4 v = g[i];
            int row = i / 50, c4 = (i % 50) * 4;
            unsigned short* d = &rbf_s[row * RSTR + c4];
            union { unsigned short s[4]; unsigned long long u; } p;
            p.s[0] = f2bf(v.x); p.s[1] = f2bf(v.y); p.s[2] = f2bf(v.z); p.s[3] = f2bf(v.w);
            *(unsigned long long*)d = p.u;
        }
        for (int i = t; i < 2048; i += 256) {
            int row = i >> 5, k = RBFD + (i & 31);
            rbf_s[row * RSTR + k] = 0;
        }
    }
    __syncthreads();

    const float bias10 = b1[col0];
    const float bias11 = b1[col0 + 16];

    // ---- GEMM1: h = ssp(rbf @ w1 + b1), store bf16 to h_s ----
#pragma unroll
    for (int m = 0; m < 4; m++) {
        f32x4 acc0 = {0.f, 0.f, 0.f, 0.f};
        f32x4 acc1 = {0.f, 0.f, 0.f, 0.f};
        const unsigned short* abase = &rbf_s[(m * 16 + l15) * RSTR + lg * 8];
#pragma unroll
        for (int kt = 0; kt < 7; kt++) {
            bf16x8 a = *(const bf16x8*)(abase + kt * 32);
            acc0 = __builtin_amdgcn_mfma_f32_16x16x32_bf16(a, B1[0][kt], acc0, 0, 0, 0);
            acc1 = __builtin_amdgcn_mfma_f32_16x16x32_bf16(a, B1[1][kt], acc1, 0, 0, 0);
        }
        const int hrow0 = m * 16 + lg * 4;        // C/D: row=(lane>>4)*4+reg, col=lane&15
#pragma unroll
        for (int r = 0; r < 4; r++) {
            h_s[(hrow0 + r) * HSTR + col0]      = f2bf(ssp(acc0[r] + bias10));
            h_s[(hrow0 + r) * HSTR + col0 + 16] = f2bf(ssp(acc1[r] + bias11));
        }
    }
    __syncthreads();

    // ---- preload B2 fragments ----
    bf16x8 B2[2][4];
#pragma unroll
    for (int nt = 0; nt < 2; nt++) {
        const int row = wv * 32 + nt * 16 + l15;
#pragma unroll
        for (int kt = 0; kt < 4; kt++)
            B2[nt][kt] = *(const bf16x8*)(w2T + (size_t)row * 128 + kt * 32 + lg * 8);
    }

    const float bias20 = b2[col0];
    const float bias21 = b2[col0 + 16];

    // ---- GEMM2: w = ssp(h @ w2 + b2); scatter-add into convw[src] ----
#pragma unroll
    for (int m = 0; m < 4; m++) {
        f32x4 acc0 = {0.f, 0.f, 0.f, 0.f};
        f32x4 acc1 = {0.f, 0.f, 0.f, 0.f};
        const unsigned short* abase = &h_s[(m * 16 + l15) * HSTR + lg * 8];
#pragma unroll
        for (int kt = 0; kt < 4; kt++) {
            bf16x8 a = *(const bf16x8*)(abase + kt * 32);
            acc0 = __builtin_amdgcn_mfma_f32_16x16x32_bf16(a, B2[0][kt], acc0, 0, 0, 0);
            acc1 = __builtin_amdgcn_mfma_f32_16x16x32_bf16(a, B2[1][kt], acc1, 0, 0, 0);
        }
        const int erow0 = m * 16 + lg * 4;
#pragma unroll
        for (int r = 0; r < 4; r++) {
            const int e = (int)e0 + erow0 + r;
            const int s = src[e];
            const size_t off = (size_t)s * CH;
            atomicAdd(&convw[off + col0],      ssp(acc0[r] + bias20));
            atomicAdd(&convw[off + col0 + 16], ssp(acc1[r] + bias21));
        }
    }
}

// ---- node side, fused (fp32): f=x@w3; conv=convw*f; y=ssp(conv@w4+b4);
//      out = x + y@w5 + b5 ----
__global__ __launch_bounds__(256) void node_all(const float* __restrict__ x,
                                                const float* __restrict__ w3,
                                                const float* __restrict__ w4,
                                                const float* __restrict__ b4,
                                                const float* __restrict__ w5,
                                                const float* __restrict__ b5,
                                                const float* __restrict__ convw,
                                                float* __restrict__ out,
                                                int n_nodes) {
    __shared__ float A[32 * 128];
    __shared__ float B[32 * 128];
    const int t = threadIdx.x;
    const int n0 = blockIdx.x * 32;
    const int rows = min(32, n_nodes - n0);

    {   // stage x tile
        const float4* g = (const float4*)(x + (size_t)n0 * CH);
        float4* s = (float4*)A;
        for (int i = t; i < rows * 32; i += 256) s[i] = g[i];
    }
    __syncthreads();

    const int c = t & 127, eh = t >> 7;
    float acc[16];

    // f = x @ w3 ; B = convw * f
#pragma unroll
    for (int i = 0; i < 16; i++) acc[i] = 0.f;
    for (int k = 0; k < 128; k += 4) {
        const float wa = w3[(k + 0) * CH + c];
        const float wb = w3[(k + 1) * CH + c];
        const float wc = w3[(k + 2) * CH + c];
        const float wd = w3[(k + 3) * CH + c];
#pragma unroll
        for (int i = 0; i < 16; i++) {
            const float4 v = *(const float4*)&A[(eh * 16 + i) * CH + k];
            acc[i] = fmaf(v.x, wa, acc[i]);
            acc[i] = fmaf(v.y, wb, acc[i]);
            acc[i] = fmaf(v.z, wc, acc[i]);
            acc[i] = fmaf(v.w, wd, acc[i]);
        }
    }
#pragma unroll
    for (int i = 0; i < 16; i++) {
        const int r = eh * 16 + i;
        B[r * 128 + c] = (r < rows) ? acc[i] * convw[((size_t)(n0 + r)) * CH + c] : 0.f;
    }
    __syncthreads();

    // y = ssp(B @ w4 + b4) -> A (x-reads all done)
#pragma unroll
    for (int i = 0; i < 16; i++) acc[i] = 0.f;
    for (int k = 0; k < 128; k += 4) {
        const float wa = w4[(k + 0) * CH + c];
        const float wb = w4[(k + 1) * CH + c];
        const float wc = w4[(k + 2) * CH + c];
        const float wd = w4[(k + 3) * CH + c];
#pragma unroll
        for (int i = 0; i < 16; i++) {
            const float4 v = *(const float4*)&B[(eh * 16 + i) * CH + k];
            acc[i] = fmaf(v.x, wa, acc[i]);
            acc[i] = fmaf(v.y, wb, acc[i]);
            acc[i] = fmaf(v.z, wc, acc[i]);
            acc[i] = fmaf(v.w, wd, acc[i]);
        }
    }
    {
        const float bias4 = b4[c];
#pragma unroll
        for (int i = 0; i < 16; i++)
            A[(eh * 16 + i) * 128 + c] = ssp(acc[i] + bias4);
    }
    __syncthreads();

    // v = A @ w5 + b5 ; out = x + v
#pragma unroll
    for (int i = 0; i < 16; i++) acc[i] = 0.f;
    for (int k = 0; k < 128; k += 4) {
        const float wa = w5[(k + 0) * CH + c];
        const float wb = w5[(k + 1) * CH + c];
        const float wc = w5[(k + 2) * CH + c];
        const float wd = w5[(k + 3) * CH + c];
#pragma unroll
        for (int i = 0; i < 16; i++) {
            const float4 v = *(const float4*)&A[(eh * 16 + i) * CH + k];
            acc[i] = fmaf(v.x, wa, acc[i]);
            acc[i] = fmaf(v.y, wb, acc[i]);
            acc[i] = fmaf(v.z, wc, acc[i]);
            acc[i] = fmaf(v.w, wd, acc[i]);
        }
    }
    {
        const float bias5 = b5[c];
#pragma unroll
        for (int i = 0; i < 16; i++) {
            const int r = eh * 16 + i;
            if (r < rows) {
                const size_t off = ((size_t)(n0 + r)) * CH + c;
                out[off] = x[off] + acc[i] + bias5;
            }
        }
    }
}

extern "C" void kernel_launch(void* const* d_in, const int* in_sizes, int n_in,
                              void* d_out, int out_size, void* d_ws, size_t ws_size,
                              hipStream_t stream) {
    const float* rbf = (const float*)d_in[0];
    const float* x   = (const float*)d_in[1];
    const int*   src = (const int*)d_in[2];
    const float* w1  = (const float*)d_in[3];
    const float* b1  = (const float*)d_in[4];
    const float* w2  = (const float*)d_in[5];
    const float* b2  = (const float*)d_in[6];
    const float* w3  = (const float*)d_in[7];
    const float* w4  = (const float*)d_in[8];
    const float* b4  = (const float*)d_in[9];
    const float* w5  = (const float*)d_in[10];
    const float* b5  = (const float*)d_in[11];

    float* out   = (float*)d_out;
    float* convw = (float*)d_ws;                 // [N,128] fp32 accumulator (25.6 MB)

    const size_t convBytes = (size_t)NNODES * CH * sizeof(float);
    const size_t wElems = 128 * K1P + 128 * 128; // 45056
    unsigned short* w1T;
    if (ws_size >= convBytes + wElems * 2)
        w1T = (unsigned short*)((char*)d_ws + convBytes);
    else
        w1T = (unsigned short*)d_out;            // d_out is dead until node_all
    unsigned short* w2T = w1T + 128 * K1P;

    hipMemsetAsync(convw, 0, convBytes, stream);
    prep_weights<<<(int)((wElems + 255) / 256), 256, 0, stream>>>(w1, w2, w1T, w2T);
    edge_kernel<<<NEDGES / 64, 256, 0, stream>>>(rbf, b1, b2, src, w1T, w2T, convw);
    node_all<<<(NNODES + 31) / 32, 256, 0, stream>>>(x, w3, w4, b4, w5, b5, convw, out, NNODES);
}